// Round 1
// baseline (345.983 us; speedup 1.0000x reference)
//
#include <hip/hip_runtime.h>
#include <hip/hip_bf16.h>
#include <stdint.h>

// Problem: out[b,s,u] = (LN(x) @ ternary(W)) * mean|W|  (gamma scalings cancel)
// x: (4,8192,1024) fp32 -> M=32768, K=1024, N=1024, out fp32.

#define M_ROWS 32768
#define KDIM 1024
#define NDIM 1024

typedef _Float16 v8h __attribute__((ext_vector_type(8)));
typedef _Float16 v4h __attribute__((ext_vector_type(4)));
typedef float v4f __attribute__((ext_vector_type(4)));

__device__ __forceinline__ void async16(const void* g, void* l) {
    __builtin_amdgcn_global_load_lds((const __attribute__((address_space(1))) uint32_t*)g,
                                     (__attribute__((address_space(3))) uint32_t*)l,
                                     16, 0, 0);
}

// ---------------- kernel 1: sum |w| ----------------
__global__ __launch_bounds__(256) void absum_k(const float* __restrict__ w, float* __restrict__ wsum) {
    int idx = blockIdx.x * 256 + threadIdx.x;
    float4 v = ((const float4*)w)[idx];
    float s = fabsf(v.x) + fabsf(v.y) + fabsf(v.z) + fabsf(v.w);
    #pragma unroll
    for (int o = 32; o; o >>= 1) s += __shfl_xor(s, o);
    __shared__ float p[4];
    if ((threadIdx.x & 63) == 0) p[threadIdx.x >> 6] = s;
    __syncthreads();
    if (threadIdx.x == 0) atomicAdd(wsum, p[0] + p[1] + p[2] + p[3]);
}

// ---------------- kernel 2: ternarize + transpose to [n][k] f16 ----------------
__global__ __launch_bounds__(256) void quant_k(const float* __restrict__ w,
                                               const float* __restrict__ wsum,
                                               _Float16* __restrict__ wqT) {
    int idx = blockIdx.x * 256 + threadIdx.x;   // over input [k][n], coalesced read
    int k = idx >> 10, n = idx & 1023;
    float beta = wsum[0] * (1.0f / 1048576.0f);
    float q = rintf(w[idx] / (beta + 1e-5f));
    q = fminf(1.0f, fmaxf(-1.0f, q));
    wqT[(size_t)n * KDIM + k] = (_Float16)q;    // scattered 2B store, small tensor, fine
}

// ---------------- kernel 3: LayerNorm row -> f16 ----------------
__global__ __launch_bounds__(256) void ln_k(const float* __restrict__ x,
                                            const float* __restrict__ g,
                                            const float* __restrict__ b,
                                            _Float16* __restrict__ xn) {
    int row = blockIdx.x;
    int tid = threadIdx.x;
    const float4* xr = (const float4*)(x + (size_t)row * KDIM);
    float4 v = xr[tid];
    float s = v.x + v.y + v.z + v.w;
    float ss = v.x * v.x + v.y * v.y + v.z * v.z + v.w * v.w;
    #pragma unroll
    for (int o = 32; o; o >>= 1) { s += __shfl_xor(s, o); ss += __shfl_xor(ss, o); }
    __shared__ float ps[8];
    int wv = tid >> 6;
    if ((tid & 63) == 0) { ps[wv] = s; ps[4 + wv] = ss; }
    __syncthreads();
    s  = ps[0] + ps[1] + ps[2] + ps[3];
    ss = ps[4] + ps[5] + ps[6] + ps[7];
    float mu  = s * (1.0f / 1024.0f);
    float var = ss * (1.0f / 1024.0f) - mu * mu;
    float rs  = rsqrtf(var + 1e-3f);            // keras LN eps
    float4 gg = ((const float4*)g)[tid];
    float4 bb = ((const float4*)b)[tid];
    v4h o;
    o[0] = (_Float16)((v.x - mu) * rs * gg.x + bb.x);
    o[1] = (_Float16)((v.y - mu) * rs * gg.y + bb.y);
    o[2] = (_Float16)((v.z - mu) * rs * gg.z + bb.z);
    o[3] = (_Float16)((v.w - mu) * rs * gg.w + bb.w);
    *(v4h*)(xn + (size_t)row * KDIM + tid * 4) = o;
}

// ---------------- kernel 4: GEMM  out = (xn @ wqT^T) * beta ----------------
// A: [M][K] f16 (xn), B: [N][K] f16 (wqT), out: [M][N] fp32.
// 128x128 block tile, BK=64, 4 waves in 2x2, each wave 64x64 via 4x4 of 16x16x32 MFMA.
// LDS chunk-XOR swizzle: chunk (16B=8 f16) at position p in row r holds actual
// chunk p^(r&7) -> global_load_lds staging stays lane-contiguous, ds_read_b128
// sees <=2-way bank aliasing (free, m136).
__global__ __launch_bounds__(256) void gemm_k(const _Float16* __restrict__ A,
                                              const _Float16* __restrict__ B,
                                              const float* __restrict__ wsum,
                                              float* __restrict__ out) {
    __shared__ _Float16 sA[128 * 64];
    __shared__ _Float16 sB[128 * 64];
    int tid = threadIdx.x;
    int w = tid >> 6, lane = tid & 63;
    int lane16 = lane & 15, quad = lane >> 4;
    int wm = w & 1, wn = w >> 1;
    int bn0 = (blockIdx.x & 7) * 128;
    int bm0 = (blockIdx.x >> 3) * 128;

    v4f acc[4][4] = {};

    int r_sub = lane >> 3;   // 0..7: row within the 8-row staging chunk
    int p     = lane & 7;    // stored chunk position

    for (int kt = 0; kt < 16; ++kt) {
        int k0 = kt * 64;
        #pragma unroll
        for (int t = 0; t < 4; ++t) {
            int rb  = w * 32 + t * 8;          // wave-uniform LDS base row
            int row = rb + r_sub;
            int c   = p ^ (row & 7);           // actual chunk this lane fetches
            async16(A + (size_t)(bm0 + row) * KDIM + k0 + c * 8, &sA[rb * 64]);
            async16(B + (size_t)(bn0 + row) * KDIM + k0 + c * 8, &sB[rb * 64]);
        }
        __syncthreads();   // drains vmcnt (compiler emits vmcnt(0) before barrier)
        #pragma unroll
        for (int kk = 0; kk < 2; ++kk) {
            v8h af[4], bf[4];
            int cc = kk * 4 + quad;
            #pragma unroll
            for (int i = 0; i < 4; ++i) {
                int m = wm * 64 + i * 16 + lane16;
                af[i] = *(const v8h*)&sA[m * 64 + (cc ^ (m & 7)) * 8];
                int n = wn * 64 + i * 16 + lane16;
                bf[i] = *(const v8h*)&sB[n * 64 + (cc ^ (n & 7)) * 8];
            }
            #pragma unroll
            for (int i = 0; i < 4; ++i)
                #pragma unroll
                for (int j = 0; j < 4; ++j)
                    acc[i][j] = __builtin_amdgcn_mfma_f32_16x16x32_f16(af[i], bf[j], acc[i][j], 0, 0, 0);
        }
        __syncthreads();
    }

    float scale = wsum[0] * (1.0f / 1048576.0f);   // beta = mean|w|
    #pragma unroll
    for (int i = 0; i < 4; ++i) {
        int mrow = bm0 + wm * 64 + i * 16 + quad * 4;   // C/D: row=(lane>>4)*4+reg
        #pragma unroll
        for (int j = 0; j < 4; ++j) {
            int ncol = bn0 + wn * 64 + j * 16 + lane16; // C/D: col=lane&15
            float* o = out + (size_t)mrow * NDIM + ncol;
            #pragma unroll
            for (int r = 0; r < 4; ++r)
                o[(size_t)r * NDIM] = acc[i][j][r] * scale;
        }
    }
}

extern "C" void kernel_launch(void* const* d_in, const int* in_sizes, int n_in,
                              void* d_out, int out_size, void* d_ws, size_t ws_size,
                              hipStream_t stream) {
    const float* x        = (const float*)d_in[0];   // 4*8192*1024
    const float* weight   = (const float*)d_in[1];   // 1024*1024
    const float* ln_gamma = (const float*)d_in[2];   // 1024
    const float* ln_beta  = (const float*)d_in[3];   // 1024
    float* out = (float*)d_out;

    // workspace layout: [0,4) wsum | [256, 256+2MiB) wqT f16 | [+64MiB) xn f16
    float*     wsum = (float*)d_ws;
    _Float16*  wqT  = (_Float16*)((char*)d_ws + 256);
    _Float16*  xn   = (_Float16*)((char*)d_ws + 256 + (1u << 21));

    hipMemsetAsync(wsum, 0, sizeof(float), stream);
    absum_k<<<1024, 256, 0, stream>>>(weight, wsum);
    quant_k<<<4096, 256, 0, stream>>>(weight, wsum, wqT);
    ln_k<<<M_ROWS, 256, 0, stream>>>(x, ln_gamma, ln_beta, xn);
    gemm_k<<<(M_ROWS / 128) * (NDIM / 128), 256, 0, stream>>>(xn, wqT, wsum, out);
}

// Round 2
// 330.086 us; speedup vs baseline: 1.0482x; 1.0482x over previous
//
#include <hip/hip_runtime.h>
#include <hip/hip_bf16.h>
#include <stdint.h>

// out[b,s,u] = (LN(x) @ ternary(W)) * mean|W|   (gamma absmax scalings cancel)
// x: (4,8192,1024) fp32 -> M=32768, K=1024, N=1024, out fp32.

#define M_ROWS 32768
#define KDIM 1024
#define NDIM 1024

typedef _Float16 v8h __attribute__((ext_vector_type(8)));
typedef _Float16 v4h __attribute__((ext_vector_type(4)));
typedef float v4f __attribute__((ext_vector_type(4)));

__device__ __forceinline__ void async16(const void* g, void* l) {
    __builtin_amdgcn_global_load_lds((const __attribute__((address_space(1))) uint32_t*)g,
                                     (__attribute__((address_space(3))) uint32_t*)l,
                                     16, 0, 0);
}

// ---------------- kernel 1: sum |w| ----------------
__global__ __launch_bounds__(256) void absum_k(const float* __restrict__ w, float* __restrict__ wsum) {
    int idx = blockIdx.x * 256 + threadIdx.x;
    float4 v = ((const float4*)w)[idx];
    float s = fabsf(v.x) + fabsf(v.y) + fabsf(v.z) + fabsf(v.w);
    #pragma unroll
    for (int o = 32; o; o >>= 1) s += __shfl_xor(s, o);
    __shared__ float p[4];
    if ((threadIdx.x & 63) == 0) p[threadIdx.x >> 6] = s;
    __syncthreads();
    if (threadIdx.x == 0) atomicAdd(wsum, p[0] + p[1] + p[2] + p[3]);
}

// ---------------- kernel 2: ternarize + transpose via LDS (coalesced both sides) ----
// grid 256 blocks; block (bi,bj) handles w[k0:k0+64][n0:n0+64] -> wqT[n0:n0+64][k0:k0+64]
__global__ __launch_bounds__(256) void quant_k(const float* __restrict__ w,
                                               const float* __restrict__ wsum,
                                               _Float16* __restrict__ wqT) {
    __shared__ _Float16 sT[64 * 72];     // [n][k], stride 72 (16B-aligned rows)
    int t = threadIdx.x;
    int k0 = (blockIdx.x >> 4) * 64, n0 = (blockIdx.x & 15) * 64;
    float beta = wsum[0] * (1.0f / 1048576.0f);
    float inv = 1.0f / (beta + 1e-5f);
    int n_l = t & 63;
    #pragma unroll
    for (int r = 0; r < 16; ++r) {
        int k_l = (t >> 6) * 16 + r;
        float q = rintf(w[(size_t)(k0 + k_l) * NDIM + n0 + n_l] * inv);
        q = fminf(1.0f, fmaxf(-1.0f, q));
        sT[n_l * 72 + k_l] = (_Float16)q;
    }
    __syncthreads();
    int nn = t >> 2, c = t & 3;          // thread stores 32B of row nn
    v8h a = *(const v8h*)&sT[nn * 72 + c * 16];
    v8h b = *(const v8h*)&sT[nn * 72 + c * 16 + 8];
    _Float16* dst = wqT + (size_t)(n0 + nn) * KDIM + k0 + c * 16;
    *(v8h*)dst = a;
    *(v8h*)(dst + 8) = b;
}

// ---------------- kernel 3: LayerNorm, wave-per-row, no barriers ----------------
// grid 8192 blocks x 256 threads = 4 waves = 4 rows/block
__global__ __launch_bounds__(256) void ln_k(const float* __restrict__ x,
                                            const float* __restrict__ g,
                                            const float* __restrict__ b,
                                            _Float16* __restrict__ xn) {
    int tid = threadIdx.x;
    int lane = tid & 63;
    int row = blockIdx.x * 4 + (tid >> 6);
    const float4* xr = (const float4*)(x + (size_t)row * KDIM);
    float4 v[4];
    #pragma unroll
    for (int j = 0; j < 4; ++j) v[j] = xr[lane + 64 * j];
    float s = 0.f, ss = 0.f;
    #pragma unroll
    for (int j = 0; j < 4; ++j) {
        s  += v[j].x + v[j].y + v[j].z + v[j].w;
        ss += v[j].x * v[j].x + v[j].y * v[j].y + v[j].z * v[j].z + v[j].w * v[j].w;
    }
    #pragma unroll
    for (int o = 32; o; o >>= 1) { s += __shfl_xor(s, o); ss += __shfl_xor(ss, o); }
    float mu  = s * (1.0f / 1024.0f);
    float var = ss * (1.0f / 1024.0f) - mu * mu;
    float rs  = rsqrtf(var + 1e-3f);            // keras LN eps
    #pragma unroll
    for (int j = 0; j < 4; ++j) {
        int p = lane + 64 * j;
        float4 gg = ((const float4*)g)[p];
        float4 bb = ((const float4*)b)[p];
        v4h o;
        o[0] = (_Float16)((v[j].x - mu) * rs * gg.x + bb.x);
        o[1] = (_Float16)((v[j].y - mu) * rs * gg.y + bb.y);
        o[2] = (_Float16)((v[j].z - mu) * rs * gg.z + bb.z);
        o[3] = (_Float16)((v[j].w - mu) * rs * gg.w + bb.w);
        *(v4h*)(xn + (size_t)row * KDIM + p * 4) = o;
    }
}

// ---------------- kernel 4: GEMM  out = (xn @ wqT^T) * beta ----------------
// A: [M][K] f16, B: [N][K] f16, out: [M][N] fp32.
// 128x128 tile, BK=64, 2x2 waves, each wave 64x64 via 4x4 of 16x16x32 MFMA.
// XCD swizzle: blocks sharing A-rows (same bm, all 8 bn) run consecutively on
// one XCD -> A fetched once per XCD-disjoint bm set (FETCH ~90MB, was 266MB).
__global__ __launch_bounds__(256) void gemm_k(const _Float16* __restrict__ A,
                                              const _Float16* __restrict__ B,
                                              const float* __restrict__ wsum,
                                              float* __restrict__ out) {
    __shared__ _Float16 sA[128 * 64];
    __shared__ _Float16 sB[128 * 64];
    int tid = threadIdx.x;
    int w = tid >> 6, lane = tid & 63;
    int lane16 = lane & 15, quad = lane >> 4;
    int wm = w & 1, wn = w >> 1;
    int xcd   = blockIdx.x & 7;          // dispatch is round-robin across 8 XCDs
    int local = blockIdx.x >> 3;         // 0..255 within this XCD
    int bm0 = (xcd * 32 + (local >> 3)) * 128;   // disjoint bm set per XCD
    int bn0 = (local & 7) * 128;                  // bn innermost -> A-tile L2 reuse

    v4f acc[4][4] = {};

    int r_sub = lane >> 3;   // 0..7: row within the 8-row staging chunk
    int p     = lane & 7;    // stored chunk position

    for (int kt = 0; kt < 16; ++kt) {
        int k0 = kt * 64;
        #pragma unroll
        for (int t = 0; t < 4; ++t) {
            int rb  = w * 32 + t * 8;          // wave-uniform LDS base row
            int row = rb + r_sub;
            int c   = p ^ (row & 7);           // chunk-XOR swizzle
            async16(A + (size_t)(bm0 + row) * KDIM + k0 + c * 8, &sA[rb * 64]);
            async16(B + (size_t)(bn0 + row) * KDIM + k0 + c * 8, &sB[rb * 64]);
        }
        __syncthreads();
        #pragma unroll
        for (int kk = 0; kk < 2; ++kk) {
            v8h af[4], bf[4];
            int cc = kk * 4 + quad;
            #pragma unroll
            for (int i = 0; i < 4; ++i) {
                int m = wm * 64 + i * 16 + lane16;
                af[i] = *(const v8h*)&sA[m * 64 + (cc ^ (m & 7)) * 8];
                int n = wn * 64 + i * 16 + lane16;
                bf[i] = *(const v8h*)&sB[n * 64 + (cc ^ (n & 7)) * 8];
            }
            #pragma unroll
            for (int i = 0; i < 4; ++i)
                #pragma unroll
                for (int j = 0; j < 4; ++j)
                    acc[i][j] = __builtin_amdgcn_mfma_f32_16x16x32_f16(af[i], bf[j], acc[i][j], 0, 0, 0);
        }
        __syncthreads();
    }

    float scale = wsum[0] * (1.0f / 1048576.0f);   // beta = mean|w|
    #pragma unroll
    for (int i = 0; i < 4; ++i) {
        int mrow = bm0 + wm * 64 + i * 16 + quad * 4;   // C/D: row=(lane>>4)*4+reg
        #pragma unroll
        for (int j = 0; j < 4; ++j) {
            int ncol = bn0 + wn * 64 + j * 16 + lane16; // C/D: col=lane&15
            float* o = out + (size_t)mrow * NDIM + ncol;
            #pragma unroll
            for (int r = 0; r < 4; ++r)
                o[(size_t)r * NDIM] = acc[i][j][r] * scale;
        }
    }
}

extern "C" void kernel_launch(void* const* d_in, const int* in_sizes, int n_in,
                              void* d_out, int out_size, void* d_ws, size_t ws_size,
                              hipStream_t stream) {
    const float* x        = (const float*)d_in[0];   // 4*8192*1024
    const float* weight   = (const float*)d_in[1];   // 1024*1024
    const float* ln_gamma = (const float*)d_in[2];   // 1024
    const float* ln_beta  = (const float*)d_in[3];   // 1024
    float* out = (float*)d_out;

    // workspace layout: [0,4) wsum | [256, 256+2MiB) wqT f16 | [+64MiB) xn f16
    float*     wsum = (float*)d_ws;
    _Float16*  wqT  = (_Float16*)((char*)d_ws + 256);
    _Float16*  xn   = (_Float16*)((char*)d_ws + 256 + (1u << 21));

    hipMemsetAsync(wsum, 0, sizeof(float), stream);
    absum_k<<<1024, 256, 0, stream>>>(weight, wsum);
    quant_k<<<256, 256, 0, stream>>>(weight, wsum, wqT);
    ln_k<<<M_ROWS / 4, 256, 0, stream>>>(x, ln_gamma, ln_beta, xn);
    gemm_k<<<(M_ROWS / 128) * (NDIM / 128), 256, 0, stream>>>(xn, wqT, wsum, out);
}

// Round 3
// 273.973 us; speedup vs baseline: 1.2628x; 1.2048x over previous
//
#include <hip/hip_runtime.h>
#include <hip/hip_bf16.h>
#include <stdint.h>

// out[b,s,u] = (LN(x) @ ternary(W)) * mean|W|   (reference's gamma absmax cancels)
// i8 pipeline: per-ROW activation scales (finer than per-tensor, no global sync),
// ternary weights exact in i8, i32 MFMA accumulation (exact), scales in epilogue.
// x: (4,8192,1024) fp32 -> M=32768, K=1024, N=1024, out fp32.

#define M_ROWS 32768
#define KDIM 1024
#define NDIM 1024

typedef int   v4i  __attribute__((ext_vector_type(4)));
typedef int   v16i __attribute__((ext_vector_type(16)));

__device__ __forceinline__ void async16(const void* g, void* l) {
    __builtin_amdgcn_global_load_lds((const __attribute__((address_space(1))) uint32_t*)g,
                                     (__attribute__((address_space(3))) uint32_t*)l,
                                     16, 0, 0);
}

// ---------------- kernel 1: |w| partial sums (no atomics, no memset) ------------
__global__ __launch_bounds__(256) void absum_k(const float* __restrict__ w,
                                               float* __restrict__ partials) {
    int idx = blockIdx.x * 256 + threadIdx.x;
    float4 v = ((const float4*)w)[idx];
    float s = fabsf(v.x) + fabsf(v.y) + fabsf(v.z) + fabsf(v.w);
    #pragma unroll
    for (int o = 32; o; o >>= 1) s += __shfl_xor(s, o);
    __shared__ float p[4];
    if ((threadIdx.x & 63) == 0) p[threadIdx.x >> 6] = s;
    __syncthreads();
    if (threadIdx.x == 0) partials[blockIdx.x] = p[0] + p[1] + p[2] + p[3];
}

// ---------------- kernel 2: ternarize + transpose -> wqT[n][k] i8 ---------------
// Each block reduces partials itself (4 KiB from L2); block 0 publishes wsum.
__global__ __launch_bounds__(256) void quant_k(const float* __restrict__ w,
                                               const float* __restrict__ partials,
                                               char* __restrict__ wqT,
                                               float* __restrict__ wsum) {
    int t = threadIdx.x;
    float s = partials[t] + partials[t + 256] + partials[t + 512] + partials[t + 768];
    #pragma unroll
    for (int o = 32; o; o >>= 1) s += __shfl_xor(s, o);
    __shared__ float ps[4];
    if ((t & 63) == 0) ps[t >> 6] = s;
    __syncthreads();
    float total = ps[0] + ps[1] + ps[2] + ps[3];
    if (blockIdx.x == 0 && t == 0) wsum[0] = total;
    float beta = total * (1.0f / 1048576.0f);
    float inv  = 1.0f / (beta + 1e-5f);

    __shared__ char sT[64 * 80];           // [n][k], stride 80 (16B-aligned rows)
    int k0 = (blockIdx.x >> 4) * 64, n0 = (blockIdx.x & 15) * 64;
    int n_l = t & 63;
    #pragma unroll
    for (int r = 0; r < 16; ++r) {
        int k_l = (t >> 6) * 16 + r;
        float q = rintf(w[(size_t)(k0 + k_l) * NDIM + n0 + n_l] * inv);
        q = fminf(1.0f, fmaxf(-1.0f, q));
        sT[n_l * 80 + k_l] = (char)(int)q;
    }
    __syncthreads();
    int nn = t >> 2, c = t & 3;
    v4i val = *(const v4i*)&sT[nn * 80 + c * 16];
    *(v4i*)&wqT[(size_t)(n0 + nn) * KDIM + k0 + c * 16] = val;
}

// ---------------- kernel 3: LN + per-row i8 quant, wave-per-row, one pass -------
__global__ __launch_bounds__(256) void ln_q_k(const float* __restrict__ x,
                                              const float* __restrict__ g,
                                              const float* __restrict__ b,
                                              char* __restrict__ xq,
                                              float* __restrict__ rscale) {
    int tid = threadIdx.x;
    int lane = tid & 63;
    int row = blockIdx.x * 4 + (tid >> 6);
    const float4* xr = (const float4*)(x + (size_t)row * KDIM);
    float4 v[4];
    #pragma unroll
    for (int j = 0; j < 4; ++j) v[j] = xr[lane + 64 * j];
    float s = 0.f, ss = 0.f;
    #pragma unroll
    for (int j = 0; j < 4; ++j) {
        s  += v[j].x + v[j].y + v[j].z + v[j].w;
        ss += v[j].x * v[j].x + v[j].y * v[j].y + v[j].z * v[j].z + v[j].w * v[j].w;
    }
    #pragma unroll
    for (int o = 32; o; o >>= 1) { s += __shfl_xor(s, o); ss += __shfl_xor(ss, o); }
    float mu  = s * (1.0f / 1024.0f);
    float var = ss * (1.0f / 1024.0f) - mu * mu;
    float rs  = rsqrtf(var + 1e-3f);        // keras LN eps
    float xn[16];
    float mx = 0.f;
    #pragma unroll
    for (int j = 0; j < 4; ++j) {
        int p = lane + 64 * j;
        float4 gg = ((const float4*)g)[p];
        float4 bb = ((const float4*)b)[p];
        xn[4*j+0] = (v[j].x - mu) * rs * gg.x + bb.x;
        xn[4*j+1] = (v[j].y - mu) * rs * gg.y + bb.y;
        xn[4*j+2] = (v[j].z - mu) * rs * gg.z + bb.z;
        xn[4*j+3] = (v[j].w - mu) * rs * gg.w + bb.w;
        #pragma unroll
        for (int e = 0; e < 4; ++e) mx = fmaxf(mx, fabsf(xn[4*j+e]));
    }
    #pragma unroll
    for (int o = 32; o; o >>= 1) mx = fmaxf(mx, __shfl_xor(mx, o));
    mx = fmaxf(mx, 1e-20f);
    float scl = mx * (1.0f / 127.0f);
    float inv = 127.0f / mx;
    if (lane == 0) rscale[row] = scl;
    #pragma unroll
    for (int j = 0; j < 4; ++j) {
        char4 c;
        c.x = (char)(int)rintf(xn[4*j+0] * inv);
        c.y = (char)(int)rintf(xn[4*j+1] * inv);
        c.z = (char)(int)rintf(xn[4*j+2] * inv);
        c.w = (char)(int)rintf(xn[4*j+3] * inv);
        *(char4*)(xq + (size_t)row * KDIM + (lane + 64 * j) * 4) = c;
    }
}

// ---------------- kernel 4: i8 GEMM  out = (xq @ wqT^T) * rscale[m] * beta ------
// A: [M][K] i8, B: [N][K] i8, out [M][N] f32. 128x128 tile, BK=128 (8 k-iters),
// 2x2 waves, wave 64x64 via 2x2 of 32x32x32 i8 MFMA (i32 accum, exact).
// Same 128-byte-row / 8-chunk XOR-swizzled LDS geometry as the validated f16 kernel.
__global__ __launch_bounds__(256) void gemm_k(const char* __restrict__ A,
                                              const char* __restrict__ B,
                                              const float* __restrict__ wsum,
                                              const float* __restrict__ rscale,
                                              float* __restrict__ out) {
    __shared__ char sA[128 * 128];
    __shared__ char sB[128 * 128];
    int tid = threadIdx.x;
    int w = tid >> 6, lane = tid & 63;
    int half = lane >> 5, l31 = lane & 31;
    int wm = w & 1, wn = w >> 1;
    int xcd   = blockIdx.x & 7;              // round-robin across 8 XCDs
    int local = blockIdx.x >> 3;             // 0..255 within this XCD
    int bm0 = (xcd * 32 + (local >> 3)) * 128;   // disjoint bm per XCD
    int bn0 = (local & 7) * 128;                 // bn innermost -> A L2 reuse

    v16i acc[2][2] = {};

    int r_sub = lane >> 3;   // row within the 8-row staging slab
    int p     = lane & 7;    // stored chunk position

    for (int kt = 0; kt < 8; ++kt) {
        int k0 = kt * 128;
        #pragma unroll
        for (int t = 0; t < 4; ++t) {
            int rb  = w * 32 + t * 8;        // wave-uniform LDS base row
            int row = rb + r_sub;
            int c   = p ^ (row & 7);         // chunk-XOR swizzle
            async16(A + (size_t)(bm0 + row) * KDIM + k0 + c * 16, &sA[rb * 128]);
            async16(B + (size_t)(bn0 + row) * KDIM + k0 + c * 16, &sB[rb * 128]);
        }
        __syncthreads();
        #pragma unroll
        for (int kk = 0; kk < 4; ++kk) {
            v4i af[2], bf[2];
            int c16 = kk * 2 + half;         // 16B chunk holding this lane's k-run
            #pragma unroll
            for (int i = 0; i < 2; ++i) {
                int m = wm * 64 + i * 32 + l31;
                af[i] = *(const v4i*)&sA[m * 128 + (c16 ^ (m & 7)) * 16];
                int n = wn * 64 + i * 32 + l31;
                bf[i] = *(const v4i*)&sB[n * 128 + (c16 ^ (n & 7)) * 16];
            }
            #pragma unroll
            for (int i = 0; i < 2; ++i)
                #pragma unroll
                for (int j = 0; j < 2; ++j)
                    acc[i][j] = __builtin_amdgcn_mfma_i32_32x32x32_i8(af[i], bf[j], acc[i][j], 0, 0, 0);
        }
        __syncthreads();
    }

    float beta = wsum[0] * (1.0f / 1048576.0f);
    #pragma unroll
    for (int i = 0; i < 2; ++i) {
        #pragma unroll
        for (int r = 0; r < 16; ++r) {
            // C/D 32x32: col = lane&31, row = (r&3) + 8*(r>>2) + 4*(lane>>5)
            int mrow = bm0 + wm * 64 + i * 32 + (r & 3) + 8 * (r >> 2) + 4 * half;
            float sc = rscale[mrow] * beta;
            #pragma unroll
            for (int j = 0; j < 2; ++j) {
                int ncol = bn0 + wn * 64 + j * 32 + l31;
                out[(size_t)mrow * NDIM + ncol] = (float)acc[i][j][r] * sc;
            }
        }
    }
}

extern "C" void kernel_launch(void* const* d_in, const int* in_sizes, int n_in,
                              void* d_out, int out_size, void* d_ws, size_t ws_size,
                              hipStream_t stream) {
    const float* x        = (const float*)d_in[0];   // 4*8192*1024
    const float* weight   = (const float*)d_in[1];   // 1024*1024
    const float* ln_gamma = (const float*)d_in[2];   // 1024
    const float* ln_beta  = (const float*)d_in[3];   // 1024
    float* out = (float*)d_out;

    // ws layout: [0,4) wsum | [4K, 8K) partials(1024 f32) | [8K, 136K) rscale(32768 f32)
    //            [256K, 256K+1M) wqT i8 | [2M, 2M+32M) xq i8
    float* wsum     = (float*)d_ws;
    float* partials = (float*)((char*)d_ws + 4096);
    float* rscale   = (float*)((char*)d_ws + 8192);
    char*  wqT      = (char*)d_ws + (1u << 18);
    char*  xq       = (char*)d_ws + (1u << 21);

    absum_k<<<1024, 256, 0, stream>>>(weight, partials);
    quant_k<<<256, 256, 0, stream>>>(weight, partials, wqT, wsum);
    ln_q_k<<<M_ROWS / 4, 256, 0, stream>>>(x, ln_gamma, ln_beta, xq, rscale);
    gemm_k<<<(M_ROWS / 128) * (NDIM / 128), 256, 0, stream>>>(xq, wqT, wsum, rscale, out);
}